// Round 11
// baseline (1916.007 us; speedup 1.0000x reference)
//
#include <hip/hip_runtime.h>

#define DIN 128
#define PB 512            // partition blocks
#define BSH 6             // bucket shift: 64 nodes/bucket
#define BKN 64
#define MAXB 2048         // max buckets (N <= 131072)
typedef unsigned short u16;
typedef unsigned int u32;
typedef __attribute__((ext_vector_type(8))) short bf16x8;  // 8 bf16 (4 VGPRs)
typedef __attribute__((ext_vector_type(4))) float f32x4;   // 4 f32 acc

static __device__ __forceinline__ float bf_lo(u32 v) {
    union { u32 u; float f; } c;
    c.u = v << 16;
    return c.f;
}
static __device__ __forceinline__ float bf_hi(u32 v) {
    union { u32 u; float f; } c;
    c.u = v & 0xffff0000u;
    return c.f;
}
static __device__ __forceinline__ u32 f2bf(float f) {
    union { float f; u32 u; } c;
    c.f = f;
    u32 u = c.u;
    u += 0x7fffu + ((u >> 16) & 1u);   // RTNE
    return u >> 16;
}

// ---- wave-64 inclusive scan helper ----
static __device__ __forceinline__ int wave_incl_scan(int x, int lane) {
#pragma unroll
    for (int off = 1; off < 64; off <<= 1) {
        int y = __shfl_up(x, off, 64);
        if (lane >= off) x += y;
    }
    return x;
}

// ---- pass 1: per-block bucket histograms of dst>>6 (-> mat[0:M)) and src>>6 (-> mat[M:2M)) ----
__global__ __launch_bounds__(256) void hist_kernel(
    const int* __restrict__ src, const int* __restrict__ dst,
    u32* __restrict__ mat, int E, int NB2, int M) {
    __shared__ u32 hd[MAXB], hs[MAXB];
    int t = threadIdx.x, b = blockIdx.x;
    for (int j = t; j < NB2; j += 256) { hd[j] = 0; hs[j] = 0; }
    __syncthreads();
    int chunk = (E + PB - 1) / PB;
    int s = b * chunk, e = min(E, s + chunk);
    for (int i = s + t; i < e; i += 256) {
        atomicAdd(&hd[((u32)dst[i]) >> BSH], 1u);
        atomicAdd(&hs[((u32)src[i]) >> BSH], 1u);
    }
    __syncthreads();
    for (int j = t; j < NB2; j += 256) {
        mat[(size_t)j * PB + b] = hd[j];
        mat[(size_t)M + (size_t)j * PB + b] = hs[j];
    }
}

// ---- per-block exclusive scan; emits block totals ----
__global__ void scan_block_kernel(const int* __restrict__ in, int* __restrict__ out,
                                  int* __restrict__ bsums, int n) {
    __shared__ int wsum[4];
    int i = blockIdx.x * 256 + threadIdx.x;
    int lane = threadIdx.x & 63, wid = threadIdx.x >> 6;
    int v = (i < n) ? in[i] : 0;
    int sc = wave_incl_scan(v, lane);
    if (lane == 63) wsum[wid] = sc;
    __syncthreads();
    int add = 0;
    for (int w = 0; w < wid; ++w) add += wsum[w];
    if (i < n) out[i] = sc - v + add;
    if (threadIdx.x == 255) bsums[blockIdx.x] = sc + add;
}

// ---- single-block exclusive scan of block sums (in-place) ----
__global__ void scan_sums_kernel(int* __restrict__ bsums, int nb) {
    __shared__ int wsum[4];
    __shared__ int carry;
    int lane = threadIdx.x & 63, wid = threadIdx.x >> 6;
    if (threadIdx.x == 0) carry = 0;
    __syncthreads();
    for (int base = 0; base < nb; base += 256) {
        int i = base + threadIdx.x;
        int v = (i < nb) ? bsums[i] : 0;
        int sc = wave_incl_scan(v, lane);
        if (lane == 63) wsum[wid] = sc;
        __syncthreads();
        int add = carry;
        for (int w = 0; w < wid; ++w) add += wsum[w];
        if (i < nb) bsums[i] = sc - v + add;
        __syncthreads();
        if (threadIdx.x == 0) carry += wsum[0] + wsum[1] + wsum[2] + wsum[3];
        __syncthreads();
    }
}

// ---- add scanned block offsets (plain exscan finalize) ----
__global__ void add_off2_kernel(int* __restrict__ out, const int* __restrict__ bsums, int n) {
    int i = blockIdx.x * 256 + threadIdx.x;
    if (i < n) out[i] += bsums[i >> 8];
}

// ---- pass 2: partition edges; part[0:E) = (dst&63)<<24|src, part[E:2E) = src ----
__global__ __launch_bounds__(256) void part_kernel(
    const int* __restrict__ src, const int* __restrict__ dst,
    const int* __restrict__ off, u32* __restrict__ part, int E, int NB2, int M) {
    __shared__ u32 cd[MAXB], cs[MAXB];
    int t = threadIdx.x, b = blockIdx.x;
    for (int j = t; j < NB2; j += 256) {
        cd[j] = (u32)off[(size_t)j * PB + b];
        cs[j] = (u32)off[(size_t)M + (size_t)j * PB + b];
    }
    __syncthreads();
    int chunk = (E + PB - 1) / PB;
    int s = b * chunk, e = min(E, s + chunk);
    for (int i = s + t; i < e; i += 256) {
        u32 dv = (u32)dst[i], sv = (u32)src[i];
        u32 p = atomicAdd(&cd[dv >> BSH], 1u);
        part[p] = ((dv & (BKN - 1u)) << 24) | sv;
        u32 q = atomicAdd(&cs[sv >> BSH], 1u);
        part[q] = sv;
    }
}

// ---- per-bucket dual histogram -> nd (in-degree), ns (out-degree) ----
__global__ __launch_bounds__(256) void normh_kernel(
    const u32* __restrict__ part, const int* __restrict__ off,
    float* __restrict__ nd, float* __restrict__ ns, int N, int E, int NB2, int M) {
    __shared__ u32 cd[BKN], cs[BKN];
    int t = threadIdx.x, k = blockIdx.x;
    if (t < BKN) { cd[t] = 0; cs[t] = 0; }
    __syncthreads();
    int beg = off[(size_t)k * PB];
    int end = (k + 1 < NB2) ? off[(size_t)(k + 1) * PB] : E;
    for (int i = beg + t; i < end; i += 256)
        atomicAdd(&cd[part[i] >> 24], 1u);
    int beg2 = off[(size_t)M + (size_t)k * PB];
    int end2 = (k + 1 < NB2) ? off[(size_t)M + (size_t)(k + 1) * PB] : 2 * E;
    for (int i = beg2 + t; i < end2; i += 256)
        atomicAdd(&cs[part[i] & (BKN - 1u)], 1u);
    __syncthreads();
    if (t < BKN) {
        int node = k * BKN + t;
        if (node < N) {
            nd[node] = rsqrtf(fmaxf((float)cd[t], 1.0f));
            ns[node] = rsqrtf(fmaxf((float)cs[t], 1.0f));
        }
    }
}

// ---- fused gather: per 64-node dst bucket, LDS f32 accumulation ----
// t = bf16 rows [N][COLS] (as u32 [N][COLS/2]); edges streamed from part (coalesced).
// out = act(nd[node] * acc + bias): bf16 packed (OUTF32=false) or f32 (true).
template <int COLS, bool RELU, bool OUTF32>
__global__ __launch_bounds__(256) void fused_gather_kernel(
    const u32* __restrict__ t, const u32* __restrict__ part,
    const int* __restrict__ off, const float* __restrict__ nd,
    const float* __restrict__ bias, void* __restrict__ outv,
    int N, int E, int NB2) {
    constexpr int LPE = COLS / 2;     // lanes per edge (u32 = 2 cols per lane)
    constexpr int EPI = 256 / LPE;    // edges per block-iteration
    __shared__ float acc[BKN * COLS];

    int tid = threadIdx.x, k = blockIdx.x;
    for (int i = tid; i < BKN * COLS; i += 256) acc[i] = 0.f;

    int beg = off[(size_t)k * PB];
    int end = (k + 1 < NB2) ? off[(size_t)(k + 1) * PB] : E;
    int g = tid / LPE;                // edge slot within block-iteration
    int l = tid % LPE;                // u32 word within row
    __syncthreads();

    int i = beg + g;
    for (; i + 3 * EPI < end; i += 4 * EPI) {
        u32 e0 = part[i];
        u32 e1 = part[i + EPI];
        u32 e2 = part[i + 2 * EPI];
        u32 e3 = part[i + 3 * EPI];
        u32 r0 = t[(size_t)(e0 & 0xFFFFFFu) * LPE + l];
        u32 r1 = t[(size_t)(e1 & 0xFFFFFFu) * LPE + l];
        u32 r2 = t[(size_t)(e2 & 0xFFFFFFu) * LPE + l];
        u32 r3 = t[(size_t)(e3 & 0xFFFFFFu) * LPE + l];
        atomicAdd(&acc[(e0 >> 24) * COLS + 2 * l], bf_lo(r0));
        atomicAdd(&acc[(e0 >> 24) * COLS + 2 * l + 1], bf_hi(r0));
        atomicAdd(&acc[(e1 >> 24) * COLS + 2 * l], bf_lo(r1));
        atomicAdd(&acc[(e1 >> 24) * COLS + 2 * l + 1], bf_hi(r1));
        atomicAdd(&acc[(e2 >> 24) * COLS + 2 * l], bf_lo(r2));
        atomicAdd(&acc[(e2 >> 24) * COLS + 2 * l + 1], bf_hi(r2));
        atomicAdd(&acc[(e3 >> 24) * COLS + 2 * l], bf_lo(r3));
        atomicAdd(&acc[(e3 >> 24) * COLS + 2 * l + 1], bf_hi(r3));
    }
    for (; i < end; i += EPI) {
        u32 e0 = part[i];
        u32 r0 = t[(size_t)(e0 & 0xFFFFFFu) * LPE + l];
        atomicAdd(&acc[(e0 >> 24) * COLS + 2 * l], bf_lo(r0));
        atomicAdd(&acc[(e0 >> 24) * COLS + 2 * l + 1], bf_hi(r0));
    }
    __syncthreads();

    // epilogue: scale by nd, add bias, activation, store
    int n0 = k * BKN;
    for (int idx = tid; idx < BKN * (COLS / 2); idx += 256) {
        int row = idx / (COLS / 2);
        int cp = idx % (COLS / 2);
        int node = n0 + row;
        if (node < N) {
            float s = nd[node];
            float2 bv = reinterpret_cast<const float2*>(bias)[cp];
            float v0 = fmaf(acc[row * COLS + 2 * cp], s, bv.x);
            float v1 = fmaf(acc[row * COLS + 2 * cp + 1], s, bv.y);
            if (RELU) { v0 = fmaxf(v0, 0.f); v1 = fmaxf(v1, 0.f); }
            if (OUTF32) {
                float2 o; o.x = v0; o.y = v1;
                reinterpret_cast<float2*>(outv)[(size_t)node * (COLS / 2) + cp] = o;
            } else {
                reinterpret_cast<u32*>(outv)[(size_t)node * (COLS / 2) + cp] =
                    f2bf(v0) | (f2bf(v1) << 16);
            }
        }
    }
}

// ---- MFMA GEMM: out[row][:] = bf16( (A[row] @ W) * scale[row] ), row-major I/O ----
template <int DOUT, bool ABF16>
__global__ __launch_bounds__(256) void gemm_mfma_kernel(
    const void* __restrict__ Av, const float* __restrict__ W,
    const float* __restrict__ scale, u16* __restrict__ out, int n) {
    constexpr int NT = DOUT / 16;       // col tiles
    constexpr int WK = DIN + 8;         // padded k-stride in bf16 units
    __shared__ u16 Wt[DOUT * WK];

    for (int i = threadIdx.x; i < DIN * DOUT; i += 256) {
        int k = i / DOUT, c = i % DOUT;
        Wt[c * WK + k] = (u16)f2bf(W[i]);
    }

    int lane = threadIdx.x & 63;
    int wid = threadIdx.x >> 6;
    int row = blockIdx.x * 64 + wid * 16 + (lane & 15);
    int rc = min(row, n - 1);
    int kg = lane >> 4;                 // k-group 0..3

    bf16x8 afrag[4];
    if (ABF16) {
        const u16* ap = (const u16*)Av + (size_t)rc * DIN + kg * 8;
#pragma unroll
        for (int s = 0; s < 4; ++s) {
            uint4 v = *reinterpret_cast<const uint4*>(ap + s * 32);
            afrag[s] = *reinterpret_cast<bf16x8*>(&v);
        }
    } else {
        const float* ap = (const float*)Av + (size_t)rc * DIN + kg * 8;
#pragma unroll
        for (int s = 0; s < 4; ++s) {
            float4 v0 = *reinterpret_cast<const float4*>(ap + s * 32);
            float4 v1 = *reinterpret_cast<const float4*>(ap + s * 32 + 4);
            uint4 v;
            v.x = f2bf(v0.x) | (f2bf(v0.y) << 16);
            v.y = f2bf(v0.z) | (f2bf(v0.w) << 16);
            v.z = f2bf(v1.x) | (f2bf(v1.y) << 16);
            v.w = f2bf(v1.z) | (f2bf(v1.w) << 16);
            afrag[s] = *reinterpret_cast<bf16x8*>(&v);
        }
    }

    f32x4 acc[NT];
#pragma unroll
    for (int t = 0; t < NT; ++t) acc[t] = (f32x4){0.f, 0.f, 0.f, 0.f};

    __syncthreads();                    // Wt ready

#pragma unroll
    for (int t = 0; t < NT; ++t) {
        const u16* wp = Wt + (t * 16 + (lane & 15)) * WK + kg * 8;
#pragma unroll
        for (int s = 0; s < 4; ++s) {
            uint4 wv = *reinterpret_cast<const uint4*>(wp + s * 32);
            bf16x8 wfrag = *reinterpret_cast<bf16x8*>(&wv);
            acc[t] = __builtin_amdgcn_mfma_f32_16x16x32_bf16(wfrag, afrag[s], acc[t], 0, 0, 0);
        }
    }

    if (row < n) {
        float sc = scale[row];
        u16* op = out + (size_t)row * DOUT + kg * 4;
#pragma unroll
        for (int t = 0; t < NT; ++t) {
            uint2 v;
            v.x = f2bf(acc[t][0] * sc) | (f2bf(acc[t][1] * sc) << 16);
            v.y = f2bf(acc[t][2] * sc) | (f2bf(acc[t][3] * sc) << 16);
            *reinterpret_cast<uint2*>(op + t * 16) = v;
        }
    }
}

extern "C" void kernel_launch(void* const* d_in, const int* in_sizes, int n_in,
                              void* d_out, int out_size, void* d_ws, size_t ws_size,
                              hipStream_t stream) {
    const float* feature = (const float*)d_in[0];
    const int*   src     = (const int*)d_in[1];
    const int*   dst     = (const int*)d_in[2];
    const float* W1      = (const float*)d_in[3];
    const float* b1      = (const float*)d_in[4];
    const float* W2      = (const float*)d_in[5];
    const float* b2      = (const float*)d_in[6];

    const int N = in_sizes[0] / DIN;
    const int E = in_sizes[1];
    const int NB2 = (N + BKN - 1) >> BSH;     // 64-node buckets (<=2048 for N<=131072)
    const int M = NB2 * PB;                   // per-side count-matrix size
    const int M2 = 2 * M;                     // concatenated (dst|src)
    const int nbm = (M2 + 255) / 256;

    char* ws = (char*)d_ws;
    size_t off_b = 0;
    auto take = [&](size_t bytes) -> void* {
        void* p = ws + off_b;
        off_b += (bytes + 255) & ~(size_t)255;
        return p;
    };
    float* ns   = (float*)take((size_t)N * 4);
    float* nd   = (float*)take((size_t)N * 4);
    u32*   mat  = (u32*)take((size_t)M2 * 4);
    int*   off  = (int*)take((size_t)M2 * 4);
    int*   bs   = (int*)take((size_t)(nbm + 4) * 4);
    u32*   part = (u32*)take((size_t)2 * E * 4);
    u16*   t1   = (u16*)take((size_t)N * DIN * 2);  // row-major; reused as t2 [N][64]
    u16*   h2   = (u16*)take((size_t)N * DIN * 2);  // row-major

    // partition build: hist -> concatenated scan -> partition -> norms
    hist_kernel<<<PB, 256, 0, stream>>>(src, dst, mat, E, NB2, M);
    scan_block_kernel<<<nbm, 256, 0, stream>>>((const int*)mat, off, bs, M2);
    scan_sums_kernel<<<1, 256, 0, stream>>>(bs, nbm);
    add_off2_kernel<<<nbm, 256, 0, stream>>>(off, bs, M2);
    part_kernel<<<PB, 256, 0, stream>>>(src, dst, off, part, E, NB2, M);
    normh_kernel<<<NB2, 256, 0, stream>>>(part, off, nd, ns, N, E, NB2, M);

    // Layer 1: t1 = bf16((X @ W1) * ns); h2 = bf16(relu(gather(t1) * nd + b1))
    gemm_mfma_kernel<128, false><<<(N + 63) / 64, 256, 0, stream>>>(feature, W1, ns, t1, N);
    fused_gather_kernel<128, true, false><<<NB2, 256, 0, stream>>>(
        (const u32*)t1, part, off, nd, b1, h2, N, E, NB2);

    // Layer 2: t2 = bf16((h2 @ W2) * ns); out = gather(t2) * nd + b2 (f32)
    gemm_mfma_kernel<64, true><<<(N + 63) / 64, 256, 0, stream>>>(h2, W2, ns, t1, N);
    fused_gather_kernel<64, false, true><<<NB2, 256, 0, stream>>>(
        (const u32*)t1, part, off, nd, b2, d_out, N, E, NB2);
}

// Round 12
// 209.626 us; speedup vs baseline: 9.1401x; 9.1401x over previous
//
#include <hip/hip_runtime.h>

#define DIN 128
#define PB 512            // partition blocks
typedef unsigned short u16;
typedef unsigned int u32;
typedef __attribute__((ext_vector_type(8))) short bf16x8;  // 8 bf16 (4 VGPRs)
typedef __attribute__((ext_vector_type(4))) float f32x4;   // 4 f32 acc

static __device__ __forceinline__ float bf_lo(u32 v) {
    union { u32 u; float f; } c;
    c.u = v << 16;
    return c.f;
}
static __device__ __forceinline__ float bf_hi(u32 v) {
    union { u32 u; float f; } c;
    c.u = v & 0xffff0000u;
    return c.f;
}
static __device__ __forceinline__ u32 f2bf(float f) {
    union { float f; u32 u; } c;
    c.f = f;
    u32 u = c.u;
    u += 0x7fffu + ((u >> 16) & 1u);   // RTNE
    return u >> 16;
}

// ---- wave-64 inclusive scan helper ----
static __device__ __forceinline__ int wave_incl_scan(int x, int lane) {
#pragma unroll
    for (int off = 1; off < 64; off <<= 1) {
        int y = __shfl_up(x, off, 64);
        if (lane >= off) x += y;
    }
    return x;
}

// ---- pass 1: per-block bucket histograms of dst>>8 (-> mat[0:M)) and src>>8 (-> mat[M:2M)) ----
__global__ __launch_bounds__(256) void hist_kernel(
    const int* __restrict__ src, const int* __restrict__ dst,
    u32* __restrict__ mat, int E, int NB, int M) {
    __shared__ u32 hd[512], hs[512];
    int t = threadIdx.x, b = blockIdx.x;
    for (int j = t; j < NB; j += 256) { hd[j] = 0; hs[j] = 0; }
    __syncthreads();
    int chunk = (E + PB - 1) / PB;
    int s = b * chunk, e = min(E, s + chunk);
    for (int i = s + t; i < e; i += 256) {
        atomicAdd(&hd[((u32)dst[i]) >> 8], 1u);
        atomicAdd(&hs[((u32)src[i]) >> 8], 1u);
    }
    __syncthreads();
    for (int j = t; j < NB; j += 256) {
        mat[(size_t)j * PB + b] = hd[j];
        mat[(size_t)M + (size_t)j * PB + b] = hs[j];
    }
}

// ---- per-block exclusive scan; emits block totals ----
__global__ void scan_block_kernel(const int* __restrict__ in, int* __restrict__ out,
                                  int* __restrict__ bsums, int n) {
    __shared__ int wsum[4];
    int i = blockIdx.x * 256 + threadIdx.x;
    int lane = threadIdx.x & 63, wid = threadIdx.x >> 6;
    int v = (i < n) ? in[i] : 0;
    int sc = wave_incl_scan(v, lane);
    if (lane == 63) wsum[wid] = sc;
    __syncthreads();
    int add = 0;
    for (int w = 0; w < wid; ++w) add += wsum[w];
    if (i < n) out[i] = sc - v + add;
    if (threadIdx.x == 255) bsums[blockIdx.x] = sc + add;
}

// ---- single-block exclusive scan of block sums (in-place) ----
__global__ void scan_sums_kernel(int* __restrict__ bsums, int nb) {
    __shared__ int wsum[4];
    __shared__ int carry;
    int lane = threadIdx.x & 63, wid = threadIdx.x >> 6;
    if (threadIdx.x == 0) carry = 0;
    __syncthreads();
    for (int base = 0; base < nb; base += 256) {
        int i = base + threadIdx.x;
        int v = (i < nb) ? bsums[i] : 0;
        int sc = wave_incl_scan(v, lane);
        if (lane == 63) wsum[wid] = sc;
        __syncthreads();
        int add = carry;
        for (int w = 0; w < wid; ++w) add += wsum[w];
        if (i < nb) bsums[i] = sc - v + add;
        __syncthreads();
        if (threadIdx.x == 0) carry += wsum[0] + wsum[1] + wsum[2] + wsum[3];
        __syncthreads();
    }
}

// ---- add scanned block offsets (plain exscan finalize) ----
__global__ void add_off2_kernel(int* __restrict__ out, const int* __restrict__ bsums, int n) {
    int i = blockIdx.x * 256 + threadIdx.x;
    if (i < n) out[i] += bsums[i >> 8];
}

// ---- pass 2: partition edges; part[0:E) dst-tagged, part[E:2E) src (LDS cursors) ----
__global__ __launch_bounds__(256) void part_kernel(
    const int* __restrict__ src, const int* __restrict__ dst,
    const int* __restrict__ off, u32* __restrict__ part, int E, int NB, int M) {
    __shared__ u32 cd[512], cs[512];
    int t = threadIdx.x, b = blockIdx.x;
    for (int j = t; j < NB; j += 256) {
        cd[j] = (u32)off[(size_t)j * PB + b];
        cs[j] = (u32)off[(size_t)M + (size_t)j * PB + b];
    }
    __syncthreads();
    int chunk = (E + PB - 1) / PB;
    int s = b * chunk, e = min(E, s + chunk);
    for (int i = s + t; i < e; i += 256) {
        u32 dv = (u32)dst[i], sv = (u32)src[i];
        u32 p = atomicAdd(&cd[dv >> 8], 1u);
        part[p] = ((dv & 255u) << 24) | sv;
        u32 q = atomicAdd(&cs[sv >> 8], 1u);
        part[q] = sv;
    }
}

// ---- pass 3: per-bucket exact build: rowptr, nd, csr_src, ns ----
__global__ __launch_bounds__(256) void build_kernel(
    const u32* __restrict__ part, const int* __restrict__ off,
    int* __restrict__ rowptr, float* __restrict__ nd, float* __restrict__ ns,
    int* __restrict__ csr_src, int N, int E, int NB, int M) {
    __shared__ u32 lh[256];
    __shared__ u32 cur[256];
    __shared__ int wsum[4];
    int t = threadIdx.x, k = blockIdx.x;
    int lane = t & 63, wid = t >> 6;
    int node = k * 256 + t;

    int beg = off[(size_t)k * PB];
    int end = (k + 1 < NB) ? off[(size_t)(k + 1) * PB] : E;

    lh[t] = 0;
    __syncthreads();
    for (int i = beg + t; i < end; i += 256)
        atomicAdd(&lh[part[i] >> 24], 1u);
    __syncthreads();

    int cnt = (int)lh[t];
    int sc = wave_incl_scan(cnt, lane);
    if (lane == 63) wsum[wid] = sc;
    __syncthreads();
    int add = 0;
    for (int w = 0; w < wid; ++w) add += wsum[w];
    int ex = sc - cnt + add;

    if (node < N) {
        rowptr[node] = beg + ex;
        nd[node] = rsqrtf(fmaxf((float)cnt, 1.0f));
    }
    if (k == 0 && t == 0) rowptr[N] = E;
    cur[t] = (u32)(beg + ex);
    __syncthreads();

    for (int i = beg + t; i < end; i += 256) {
        u32 v = part[i];
        u32 pos = atomicAdd(&cur[v >> 24], 1u);
        csr_src[pos] = (int)(v & 0xFFFFFFu);
    }

    // src side: exact outdeg histogram -> ns (absolute offsets into part[E:2E))
    int beg2 = off[(size_t)M + (size_t)k * PB];
    int end2 = (k + 1 < NB) ? off[(size_t)M + (size_t)(k + 1) * PB] : 2 * E;
    __syncthreads();
    lh[t] = 0;
    __syncthreads();
    for (int i = beg2 + t; i < end2; i += 256)
        atomicAdd(&lh[part[i] & 255u], 1u);
    __syncthreads();
    if (node < N) ns[node] = rsqrtf(fmaxf((float)lh[t], 1.0f));
}

// ---- gather (layer 1): 2 nodes per wave (lanes 0-31 / 32-63), uint2 (8B) per lane ----
// h2 = relu(nd * sum t1[src] + b1); t1/h2 bf16 128-wide (row = 32 uint2).
__global__ __launch_bounds__(256, 8) void gather128_kernel(
    const uint2* __restrict__ tp, const int* __restrict__ rowptr,
    const int* __restrict__ csr_src, const float* __restrict__ nd,
    const float* __restrict__ bias, uint2* __restrict__ out, int N) {
    int tid = threadIdx.x;
    int lane = tid & 63;
    int half = lane >> 5;
    int w = lane & 31;                 // word pair: cols 4w..4w+3
    int node = blockIdx.x * 8 + ((tid >> 6) << 1) + half;
    bool valid = node < N;
    int nc = valid ? node : 0;
    int beg = rowptr[nc];
    int cnt = valid ? (rowptr[nc + 1] - beg) : 0;
    const int* ip = csr_src + beg;

    float a0 = 0.f, a1 = 0.f, a2 = 0.f, a3 = 0.f;
    int j = 0;
    for (; j + 8 <= cnt; j += 8) {
        int s[8];
#pragma unroll
        for (int k = 0; k < 8; ++k) s[k] = ip[j + k];
        uint2 v[8];
#pragma unroll
        for (int k = 0; k < 8; ++k) v[k] = tp[(size_t)s[k] * 32 + w];
#pragma unroll
        for (int k = 0; k < 8; ++k) {
            a0 += bf_lo(v[k].x); a1 += bf_hi(v[k].x);
            a2 += bf_lo(v[k].y); a3 += bf_hi(v[k].y);
        }
    }
    if (j + 4 <= cnt) {
        int s[4];
#pragma unroll
        for (int k = 0; k < 4; ++k) s[k] = ip[j + k];
        uint2 v[4];
#pragma unroll
        for (int k = 0; k < 4; ++k) v[k] = tp[(size_t)s[k] * 32 + w];
#pragma unroll
        for (int k = 0; k < 4; ++k) {
            a0 += bf_lo(v[k].x); a1 += bf_hi(v[k].x);
            a2 += bf_lo(v[k].y); a3 += bf_hi(v[k].y);
        }
        j += 4;
    }
    if (j + 2 <= cnt) {
        uint2 v0 = tp[(size_t)ip[j] * 32 + w];
        uint2 v1 = tp[(size_t)ip[j + 1] * 32 + w];
        a0 += bf_lo(v0.x) + bf_lo(v1.x); a1 += bf_hi(v0.x) + bf_hi(v1.x);
        a2 += bf_lo(v0.y) + bf_lo(v1.y); a3 += bf_hi(v0.y) + bf_hi(v1.y);
        j += 2;
    }
    if (j < cnt) {
        uint2 v0 = tp[(size_t)ip[j] * 32 + w];
        a0 += bf_lo(v0.x); a1 += bf_hi(v0.x);
        a2 += bf_lo(v0.y); a3 += bf_hi(v0.y);
    }

    if (valid) {
        float sc = nd[nc];
        float4 bv = reinterpret_cast<const float4*>(bias)[w];
        float r0 = fmaxf(a0 * sc + bv.x, 0.f);
        float r1 = fmaxf(a1 * sc + bv.y, 0.f);
        float r2 = fmaxf(a2 * sc + bv.z, 0.f);
        float r3 = fmaxf(a3 * sc + bv.w, 0.f);
        uint2 o;
        o.x = f2bf(r0) | (f2bf(r1) << 16);
        o.y = f2bf(r2) | (f2bf(r3) << 16);
        out[(size_t)node * 32 + w] = o;
    }
}

// ---- gather (layer 2): 2 nodes per wave, u32 (4B) per lane; out f32 64-wide ----
__global__ __launch_bounds__(256, 8) void gather64_kernel(
    const u32* __restrict__ tp, const int* __restrict__ rowptr,
    const int* __restrict__ csr_src, const float* __restrict__ nd,
    const float* __restrict__ bias, float2* __restrict__ out, int N) {
    int tid = threadIdx.x;
    int lane = tid & 63;
    int half = lane >> 5;
    int w = lane & 31;                 // cols 2w, 2w+1
    int node = blockIdx.x * 8 + ((tid >> 6) << 1) + half;
    bool valid = node < N;
    int nc = valid ? node : 0;
    int beg = rowptr[nc];
    int cnt = valid ? (rowptr[nc + 1] - beg) : 0;
    const int* ip = csr_src + beg;

    float a0 = 0.f, a1 = 0.f;
    int j = 0;
    for (; j + 8 <= cnt; j += 8) {
        int s[8];
#pragma unroll
        for (int k = 0; k < 8; ++k) s[k] = ip[j + k];
        u32 v[8];
#pragma unroll
        for (int k = 0; k < 8; ++k) v[k] = tp[(size_t)s[k] * 32 + w];
#pragma unroll
        for (int k = 0; k < 8; ++k) { a0 += bf_lo(v[k]); a1 += bf_hi(v[k]); }
    }
    if (j + 4 <= cnt) {
        int s[4];
#pragma unroll
        for (int k = 0; k < 4; ++k) s[k] = ip[j + k];
        u32 v[4];
#pragma unroll
        for (int k = 0; k < 4; ++k) v[k] = tp[(size_t)s[k] * 32 + w];
#pragma unroll
        for (int k = 0; k < 4; ++k) { a0 += bf_lo(v[k]); a1 += bf_hi(v[k]); }
        j += 4;
    }
    if (j + 2 <= cnt) {
        u32 v0 = tp[(size_t)ip[j] * 32 + w];
        u32 v1 = tp[(size_t)ip[j + 1] * 32 + w];
        a0 += bf_lo(v0) + bf_lo(v1);
        a1 += bf_hi(v0) + bf_hi(v1);
        j += 2;
    }
    if (j < cnt) {
        u32 v0 = tp[(size_t)ip[j] * 32 + w];
        a0 += bf_lo(v0); a1 += bf_hi(v0);
    }

    if (valid) {
        float sc = nd[nc];
        float2 bv = reinterpret_cast<const float2*>(bias)[w];
        float2 o;
        o.x = a0 * sc + bv.x;
        o.y = a1 * sc + bv.y;
        out[(size_t)node * 32 + w] = o;
    }
}

// ---- MFMA GEMM: out[row][:] = bf16( (A[row] @ W) * scale[row] ), W f32 [DIN][DOUT] ----
template <int DOUT, bool ABF16>
__global__ __launch_bounds__(256) void gemm_mfma_kernel(
    const void* __restrict__ Av, const float* __restrict__ W,
    const float* __restrict__ scale, u16* __restrict__ out, int n) {
    constexpr int NT = DOUT / 16;       // col tiles
    constexpr int WK = DIN + 8;         // padded k-stride in bf16 units
    __shared__ u16 Wt[DOUT * WK];

    for (int i = threadIdx.x; i < DIN * DOUT; i += 256) {
        int k = i / DOUT, c = i % DOUT;
        Wt[c * WK + k] = (u16)f2bf(W[i]);
    }

    int lane = threadIdx.x & 63;
    int wid = threadIdx.x >> 6;
    int row = blockIdx.x * 64 + wid * 16 + (lane & 15);
    int rc = min(row, n - 1);
    int kg = lane >> 4;                 // k-group 0..3

    bf16x8 afrag[4];
    if (ABF16) {
        const u16* ap = (const u16*)Av + (size_t)rc * DIN + kg * 8;
#pragma unroll
        for (int s = 0; s < 4; ++s) {
            uint4 v = *reinterpret_cast<const uint4*>(ap + s * 32);
            afrag[s] = *reinterpret_cast<bf16x8*>(&v);
        }
    } else {
        const float* ap = (const float*)Av + (size_t)rc * DIN + kg * 8;
#pragma unroll
        for (int s = 0; s < 4; ++s) {
            float4 v0 = *reinterpret_cast<const float4*>(ap + s * 32);
            float4 v1 = *reinterpret_cast<const float4*>(ap + s * 32 + 4);
            uint4 v;
            v.x = f2bf(v0.x) | (f2bf(v0.y) << 16);
            v.y = f2bf(v0.z) | (f2bf(v0.w) << 16);
            v.z = f2bf(v1.x) | (f2bf(v1.y) << 16);
            v.w = f2bf(v1.z) | (f2bf(v1.w) << 16);
            afrag[s] = *reinterpret_cast<bf16x8*>(&v);
        }
    }

    f32x4 acc[NT];
#pragma unroll
    for (int t = 0; t < NT; ++t) acc[t] = (f32x4){0.f, 0.f, 0.f, 0.f};

    __syncthreads();                    // Wt ready

#pragma unroll
    for (int t = 0; t < NT; ++t) {
        const u16* wp = Wt + (t * 16 + (lane & 15)) * WK + kg * 8;
#pragma unroll
        for (int s = 0; s < 4; ++s) {
            uint4 wv = *reinterpret_cast<const uint4*>(wp + s * 32);
            bf16x8 wfrag = *reinterpret_cast<bf16x8*>(&wv);
            acc[t] = __builtin_amdgcn_mfma_f32_16x16x32_bf16(wfrag, afrag[s], acc[t], 0, 0, 0);
        }
    }

    if (row < n) {
        float sc = scale[row];
        u16* op = out + (size_t)row * DOUT + kg * 4;
#pragma unroll
        for (int t = 0; t < NT; ++t) {
            uint2 v;
            v.x = f2bf(acc[t][0] * sc) | (f2bf(acc[t][1] * sc) << 16);
            v.y = f2bf(acc[t][2] * sc) | (f2bf(acc[t][3] * sc) << 16);
            *reinterpret_cast<uint2*>(op + t * 16) = v;
        }
    }
}

extern "C" void kernel_launch(void* const* d_in, const int* in_sizes, int n_in,
                              void* d_out, int out_size, void* d_ws, size_t ws_size,
                              hipStream_t stream) {
    const float* feature = (const float*)d_in[0];
    const int*   src     = (const int*)d_in[1];
    const int*   dst     = (const int*)d_in[2];
    const float* W1      = (const float*)d_in[3];
    const float* b1      = (const float*)d_in[4];
    const float* W2      = (const float*)d_in[5];
    const float* b2      = (const float*)d_in[6];

    const int N = in_sizes[0] / DIN;
    const int E = in_sizes[1];
    const int NB = (N + 255) >> 8;            // buckets (<=512 for N<=131072)
    const int M = NB * PB;                    // per-side count-matrix size
    const int M2 = 2 * M;                     // concatenated (dst|src)
    const int nbm = (M2 + 255) / 256;

    char* ws = (char*)d_ws;
    size_t off_b = 0;
    auto take = [&](size_t bytes) -> void* {
        void* p = ws + off_b;
        off_b += (bytes + 255) & ~(size_t)255;
        return p;
    };
    float* ns      = (float*)take((size_t)N * 4);
    float* nd      = (float*)take((size_t)N * 4);
    int*   rowptr  = (int*)take((size_t)(N + 1) * 4);
    int*   csr_src = (int*)take((size_t)E * 4);
    u32*   mat     = (u32*)take((size_t)M2 * 4);
    int*   off     = (int*)take((size_t)M2 * 4);
    int*   bs      = (int*)take((size_t)(nbm + 4) * 4);
    u32*   part    = (u32*)take((size_t)2 * E * 4);
    u16*   t1      = (u16*)take((size_t)N * DIN * 2);  // reused as t2 (N*64 bf16)
    u16*   h2      = (u16*)take((size_t)N * DIN * 2);

    // CSR build: hist -> single concatenated scan -> partition -> per-bucket build
    hist_kernel<<<PB, 256, 0, stream>>>(src, dst, mat, E, NB, M);
    scan_block_kernel<<<nbm, 256, 0, stream>>>((const int*)mat, off, bs, M2);
    scan_sums_kernel<<<1, 256, 0, stream>>>(bs, nbm);
    add_off2_kernel<<<nbm, 256, 0, stream>>>(off, bs, M2);
    part_kernel<<<PB, 256, 0, stream>>>(src, dst, off, part, E, NB, M);
    build_kernel<<<NB, 256, 0, stream>>>(part, off, rowptr, nd, ns, csr_src, N, E, NB, M);

    // Layer 1: t1 = bf16((X @ W1) * ns); h2 = bf16(relu(gather(t1) * nd + b1))
    gemm_mfma_kernel<128, false><<<(N + 63) / 64, 256, 0, stream>>>(feature, W1, ns, t1, N);
    gather128_kernel<<<(N + 7) / 8, 256, 0, stream>>>(
        (const uint2*)t1, rowptr, csr_src, nd, b1, (uint2*)h2, N);

    // Layer 2: t2 = bf16((h2 @ W2) * ns); out = gather(t2) * nd + b2 (f32)
    gemm_mfma_kernel<64, true><<<(N + 63) / 64, 256, 0, stream>>>(h2, W2, ns, t1, N);
    gather64_kernel<<<(N + 7) / 8, 256, 0, stream>>>(
        (const u32*)t1, rowptr, csr_src, nd, b2, (float2*)d_out, N);
}